// Round 11
// baseline (271.618 us; speedup 1.0000x reference)
//
#include <hip/hip_runtime.h>

// ---------------------------------------------------------------------------
// MySelfAttention: out = softmax((X Wq)(X Wk)^T / sqrt(dh) + mask) (X Wv)
// B=2, S=2048, H=16, dh=64, DIM=1024. fp32 in/out, bf16 MFMA internally.
// R11: attn gets BOTH 4 waves/SIMD AND 2:1 MFMA:LDS-read by fitting 64q/wave
//      in 128 VGPR: Q-frags reloaded from L2 each body (loop-invariant),
//      q-groups processed sequentially (one p[32] live). 512 blk x 8 waves
//      (2qg x 4tq over a staged 128-t K/V pair), LDS 69.6KB -> 2 blk/CU.
//      V^T swizzle widened to 128-t blocks. 4-way tq combine in dead LDS.
//      convert_x + transpose_w merged into one launch.
// ---------------------------------------------------------------------------

typedef __attribute__((ext_vector_type(4))) float f32x4;
typedef __attribute__((ext_vector_type(16))) float f32x16;
typedef __attribute__((ext_vector_type(8))) __bf16 bf16x8;

#define DEV static __device__ __forceinline__

constexpr int S_ = 2048;
constexpr int H_ = 16;
constexpr int DH_ = 64;
constexpr int M_ = 2 * S_;       // 4096 rows (b,s)
constexpr int N3_ = 3 * 1024;    // 3072 cols (q|k|v)
constexpr int K_ = 1024;
constexpr float LOG2E = 1.44269504088896340736f;

DEV unsigned short f2bf(float f) {
  unsigned u = __builtin_bit_cast(unsigned, f);
  u += 0x7fffu + ((u >> 16) & 1u);   // round-nearest-even
  return (unsigned short)(u >> 16);
}

DEV unsigned cvt_pk(float lo, float hi) {
  unsigned d;
  asm("v_cvt_pk_bf16_f32 %0, %1, %2" : "=v"(d) : "v"(lo), "v"(hi));
  return d;
}

DEV void gload_lds16(const void* g, void* l) {
  __builtin_amdgcn_global_load_lds(
      (const __attribute__((address_space(1))) unsigned int*)g,
      (__attribute__((address_space(3))) unsigned int*)l, 16, 0, 0);
}

// XOR swizzle: row-major tile with 128B rows, byte ^= (row&7)<<4
DEV int kswz(int row, int colb) { return row * 128 + (colb ^ ((row & 7) << 4)); }

// ---------------------------------------------------------------------------
// Kernel 1: merged prep. id<3072: transpose+convert W (z=id/1024);
// else: convert X chunk. Saves one launch.
// ---------------------------------------------------------------------------
__global__ __launch_bounds__(256) void prep(
    const float* __restrict__ X, const float* __restrict__ Wq,
    const float* __restrict__ Wk, const float* __restrict__ Wv,
    unsigned short* __restrict__ Xbf, unsigned short* __restrict__ Wt) {
  __shared__ float tile[32][33];
  const int id = blockIdx.x;
  const int tid = threadIdx.x;
  if (id < 3072) {
    int z = id >> 10, rem = id & 1023;
    const float* W = (z == 0) ? Wq : (z == 1) ? Wk : Wv;
    int n0 = (rem & 31) * 32, k0 = (rem >> 5) * 32;
    int tx = tid & 31, ty = tid >> 5;   // 32 x 8
    for (int i = 0; i < 4; ++i)
      tile[ty + i * 8][tx] = W[(size_t)(k0 + ty + i * 8) * 1024 + n0 + tx];
    __syncthreads();
    for (int i = 0; i < 4; ++i)
      Wt[(size_t)(z * 1024 + n0 + ty + i * 8) * 1024 + k0 + tx] =
          f2bf(tile[tx][ty + i * 8]);
  } else {
    int idx = ((id - 3072) * 256 + tid) * 8;
    float4 a = *(const float4*)(X + idx);
    float4 b = *(const float4*)(X + idx + 4);
    unsigned short r[8];
    r[0] = f2bf(a.x); r[1] = f2bf(a.y); r[2] = f2bf(a.z); r[3] = f2bf(a.w);
    r[4] = f2bf(b.x); r[5] = f2bf(b.y); r[6] = f2bf(b.z); r[7] = f2bf(b.w);
    *(uint4*)(Xbf + idx) = *(uint4*)r;
  }
}

// ---------------------------------------------------------------------------
// Kernel 2: QKV GEMM (R7 structure). Epilogue: bias; Q *= 0.125*log2e plain;
// K pre-swizzled (dd ^ (ss&7)<<3); V^T pre-swizzled per 128-t block
// ((ss&127) ^ (dd&15)<<3) for attn's 256B-row LDS tiles.
// ---------------------------------------------------------------------------
__global__ __launch_bounds__(256, 2) void qkv_gemm(
    const unsigned short* __restrict__ Xbf, const unsigned short* __restrict__ Wt,
    const float* __restrict__ bq, const float* __restrict__ bk,
    const float* __restrict__ bv, unsigned short* __restrict__ Qw,
    unsigned short* __restrict__ Kw, unsigned short* __restrict__ Vt) {
  __shared__ unsigned short Abuf[128 * 64];
  __shared__ unsigned short Bbuf[128 * 64];
  int tid = threadIdx.x;
  int w = tid >> 6, l = tid & 63;
  int row16 = l & 15, kg = l >> 4;
  int mBase = blockIdx.y * 128, nBase = blockIdx.x * 128;
  int wm = w >> 1, wn = w & 1;

  f32x4 acc[4][4] = {};

  const int grow = l >> 3;
  const int gcol = ((l & 7) ^ grow) * 8;

  for (int kt = 0; kt < K_ / 64; ++kt) {
    int k0 = kt * 64;
    __syncthreads();
#pragma unroll
    for (int j = 0; j < 4; ++j) {
      int c1k = w * 4 + j;
      int r = c1k * 8 + grow;
      gload_lds16(Xbf + (size_t)(mBase + r) * K_ + k0 + gcol,
                  (char*)Abuf + c1k * 1024);
      gload_lds16(Wt + (size_t)(nBase + r) * K_ + k0 + gcol,
                  (char*)Bbuf + c1k * 1024);
    }
    __syncthreads();
#pragma unroll
    for (int kk = 0; kk < 2; ++kk) {
      bf16x8 af[4], bfr[4];
#pragma unroll
      for (int m = 0; m < 4; ++m)
        af[m] = *(const bf16x8*)((const char*)Abuf +
                 kswz(wm * 64 + m * 16 + row16, kk * 64 + kg * 16));
#pragma unroll
      for (int n = 0; n < 4; ++n)
        bfr[n] = *(const bf16x8*)((const char*)Bbuf +
                  kswz(wn * 64 + n * 16 + row16, kk * 64 + kg * 16));
#pragma unroll
      for (int m = 0; m < 4; ++m)
#pragma unroll
        for (int n = 0; n < 4; ++n)
          acc[m][n] = __builtin_amdgcn_mfma_f32_16x16x32_bf16(af[m], bfr[n],
                                                              acc[m][n], 0, 0, 0);
    }
  }

#pragma unroll
  for (int n = 0; n < 4; ++n) {
    int gn = nBase + wn * 64 + n * 16 + row16;
    int which = gn >> 10;
    int nn = gn & 1023;
    float bias = (which == 0 ? bq : which == 1 ? bk : bv)[nn];
    unsigned short* dst = (which == 0) ? Qw : (which == 1) ? Kw : Vt;
    float scl = (which == 0) ? 0.125f * LOG2E : 1.0f;
    int hh = nn >> 6, dd = nn & 63;
#pragma unroll
    for (int m = 0; m < 4; ++m) {
      int gm0 = mBase + wm * 64 + m * 16 + kg * 4;
#pragma unroll
      for (int j = 0; j < 4; ++j) {
        int gm = gm0 + j;
        int bb = gm >> 11, ss = gm & 2047;
        float v = (acc[m][n][j] + bias) * scl;
        size_t idx;
        if (which == 2) {
          int cs = (ss & ~127) | ((ss & 127) ^ ((dd & 15) << 3));
          idx = ((size_t)(bb * H_ + hh) * DH_ + dd) * S_ + cs;
        } else if (which == 1) {
          idx = ((size_t)(bb * H_ + hh) * S_ + ss) * DH_ + (dd ^ ((ss & 7) << 3));
        } else {
          idx = ((size_t)(bb * H_ + hh) * S_ + ss) * DH_ + dd;
        }
        dst[idx] = f2bf(v);
      }
    }
  }
}

// ---------------------------------------------------------------------------
// Kernel 3: flash attention. 512 blocks x 512 thr (8 waves = 2qg x 4tq).
// Wave: 64 q (groups A,B), 32 t per body (its quarter of the staged pair).
// LDS: [0,4096) l-scratch | K buf c at 4096+c*32768 | V buf c at 20480+c*32768.
// Q reloaded from L2 per body; groups processed sequentially (reg pressure).
// ---------------------------------------------------------------------------
__global__ __launch_bounds__(512, 4) void attn_fwd(
    const unsigned short* __restrict__ Qw, const unsigned short* __restrict__ Kw,
    const unsigned short* __restrict__ Vt, const float* __restrict__ mask,
    float* __restrict__ out) {
  __shared__ __align__(16) char LDS[69632];

  const int tid = threadIdx.x;
  const int w = tid >> 6, l = tid & 63;
  const int qg = w >> 2, tq = w & 3;
  const int lq = l & 31, h = l >> 5;
  const int wgid = blockIdx.x;              // 0..511
  const int xcd = wgid & 7, ixd = wgid >> 3;
  const int bh = xcd + 8 * (ixd >> 4);      // 0..31, 4 bh per XCD
  const int qt = ixd & 15;
  const int b = bh >> 4, hh = bh & 15;
  const int q0w = qt * 128 + qg * 64;

  const char* Kb = (const char*)(Kw + (size_t)bh * S_ * DH_);   // pre-swizzled
  const char* Vb = (const char*)(Vt + (size_t)bh * DH_ * S_);   // pre-swizzled
  const unsigned short* qAp = Qw + ((size_t)bh * S_ + q0w + lq) * DH_;
  const unsigned short* qBp = qAp + 32 * DH_;
  const float* mp = mask + (size_t)b * S_;

  // staging source offsets (per-lane, loop-invariant)
  int voff[2];
#pragma unroll
  for (int i = 0; i < 2; ++i) {
    int Lb = (w * 2 + i) * 1024 + l * 16;
    voff[i] = (Lb >> 8) * (S_ * 2) + (Lb & 255);
  }

  // fragment read bases (loop-invariant; dbuf via +cur*32768 immediate)
  int rbK[4], rbV[2];
#pragma unroll
  for (int kk = 0; kk < 4; ++kk)
    rbK[kk] = 4096 + (tq * 32 + lq) * 128 + ((kk * 32 + h * 16) ^ ((lq & 7) << 4));
#pragma unroll
  for (int s = 0; s < 2; ++s)
    rbV[s] = 20480 + lq * 256 + ((tq * 64 + s * 32 + h * 16) ^ ((lq & 15) << 4));

  auto stage = [&](int p, int buf) __attribute__((always_inline)) {
#pragma unroll
    for (int i = 0; i < 2; ++i) {
      const int c = w * 2 + i;
      gload_lds16(Kb + (size_t)p * 16384 + c * 1024 + l * 16,
                  LDS + 4096 + buf * 32768 + c * 1024);
      gload_lds16(Vb + (size_t)p * 256 + voff[i],
                  LDS + 20480 + buf * 32768 + c * 1024);
    }
  };

  stage(0, 0);
  __syncthreads();

  float lA = 0.f, lB = 0.f;
  f32x16 OA0 = {}, OA1 = {}, OB0 = {}, OB1 = {};

  auto body = [&](int p, int cur) __attribute__((always_inline)) {
    if (p < 15) stage(p + 1, cur ^ 1);

    // mask for this quarter (shared by both q-groups), premultiplied
    f32x4 mk[4];
#pragma unroll
    for (int r2 = 0; r2 < 4; ++r2) {
      float4 m4 = *(const float4*)(mp + p * 128 + tq * 32 + 8 * r2 + 4 * h);
      mk[r2][0] = m4.x * LOG2E; mk[r2][1] = m4.y * LOG2E;
      mk[r2][2] = m4.z * LOG2E; mk[r2][3] = m4.w * LOG2E;
    }

    unsigned wA[8], wB[8];
    // ---- group B then A (sequential to keep one p[] live) ----
#pragma unroll
    for (int g = 0; g < 2; ++g) {
      const unsigned short* qp = g ? qAp : qBp;
      f32x16 pq;
#pragma unroll
      for (int r2 = 0; r2 < 4; ++r2)
#pragma unroll
        for (int c = 0; c < 4; ++c) pq[4 * r2 + c] = mk[r2][c];

      __builtin_amdgcn_s_setprio(1);
#pragma unroll
      for (int kk = 0; kk < 4; ++kk) {
        bf16x8 qf = *(const bf16x8*)(qp + kk * 16 + h * 8);
        bf16x8 kf = *(const bf16x8*)(LDS + rbK[kk] + cur * 32768);
        pq = __builtin_amdgcn_mfma_f32_32x32x16_bf16(kf, qf, pq, 0, 0, 0);
      }
      __builtin_amdgcn_s_setprio(0);

#pragma unroll
      for (int i = 0; i < 16; ++i) pq[i] = __builtin_amdgcn_exp2f(pq[i]);

      float s8[8];
#pragma unroll
      for (int i = 0; i < 8; ++i) s8[i] = pq[i] + pq[i + 8];
      float rs = ((s8[0] + s8[1]) + (s8[2] + s8[3])) +
                 ((s8[4] + s8[5]) + (s8[6] + s8[7]));
      rs += __shfl_xor(rs, 32, 64);
      if (g) lA += rs; else lB += rs;

      unsigned* W = g ? wA : wB;
#pragma unroll
      for (int r2 = 0; r2 < 4; ++r2) {
        W[2 * r2]     = cvt_pk(pq[4 * r2 + 0], pq[4 * r2 + 1]);
        W[2 * r2 + 1] = cvt_pk(pq[4 * r2 + 2], pq[4 * r2 + 3]);
      }
    }

    // ---- PV: 2 t-slices; each V read feeds both groups ----
    __builtin_amdgcn_s_setprio(1);
#pragma unroll
    for (int s = 0; s < 2; ++s) {
      const int base = s * 4;
      unsigned sA0 = h ? wA[base + 0] : wA[base + 2];
      unsigned sA1 = h ? wA[base + 1] : wA[base + 3];
      unsigned sB0 = h ? wB[base + 0] : wB[base + 2];
      unsigned sB1 = h ? wB[base + 1] : wB[base + 3];
      unsigned cA0 = (unsigned)__shfl_xor((int)sA0, 32, 64);
      unsigned cA1 = (unsigned)__shfl_xor((int)sA1, 32, 64);
      unsigned cB0 = (unsigned)__shfl_xor((int)sB0, 32, 64);
      unsigned cB1 = (unsigned)__shfl_xor((int)sB1, 32, 64);
      uint4 fA, fB;
      fA.x = h ? cA0 : wA[base + 0];
      fA.y = h ? cA1 : wA[base + 1];
      fA.z = h ? wA[base + 2] : cA0;
      fA.w = h ? wA[base + 3] : cA1;
      fB.x = h ? cB0 : wB[base + 0];
      fB.y = h ? cB1 : wB[base + 1];
      fB.z = h ? wB[base + 2] : cB0;
      fB.w = h ? wB[base + 3] : cB1;
      bf16x8 pfA = __builtin_bit_cast(bf16x8, fA);
      bf16x8 pfB = __builtin_bit_cast(bf16x8, fB);
      bf16x8 vf0 = *(const bf16x8*)(LDS + rbV[s] + cur * 32768);
      bf16x8 vf1 = *(const bf16x8*)(LDS + rbV[s] + 8192 + cur * 32768);
      OA0 = __builtin_amdgcn_mfma_f32_32x32x16_bf16(vf0, pfA, OA0, 0, 0, 0);
      OB0 = __builtin_amdgcn_mfma_f32_32x32x16_bf16(vf0, pfB, OB0, 0, 0, 0);
      OA1 = __builtin_amdgcn_mfma_f32_32x32x16_bf16(vf1, pfA, OA1, 0, 0, 0);
      OB1 = __builtin_amdgcn_mfma_f32_32x32x16_bf16(vf1, pfB, OB1, 0, 0, 0);
    }
    __builtin_amdgcn_s_setprio(0);

    __syncthreads();
  };

#pragma unroll 1
  for (int pp = 0; pp < 8; ++pp) {
    body(2 * pp, 0);
    body(2 * pp + 1, 1);
  }

  // ---- 4-way tq combine (no-max softmax partials are additive) ----
  float* Lp = (float*)LDS;                 // [0,4096)
  char* SB = LDS + 4096;                   // reuse KV bufs (dead)
  const int lbase = ((qg * 4 + tq) * 64 + l) * 2;
  Lp[lbase] = lA;
  Lp[lbase + 1] = lB;

  const int sx = (l & 15) << 4;
  auto slotW = [&](int sid) __attribute__((always_inline)) {
    char* sb = SB + sid * 16384 + l * 256;
    const f32x16* Os[4] = {&OA0, &OA1, &OB0, &OB1};
#pragma unroll
    for (int r = 0; r < 4; ++r)
#pragma unroll
      for (int i = 0; i < 4; ++i) {
        f32x4 v;
#pragma unroll
        for (int c = 0; c < 4; ++c) v[c] = (*Os[r])[i * 4 + c];
        *(f32x4*)(sb + (((r * 4 + i) * 16) ^ sx)) = v;
      }
  };
  auto slotR = [&](int sid) __attribute__((always_inline)) {
    char* sb = SB + sid * 16384 + l * 256;
    f32x16* Os[4] = {&OA0, &OA1, &OB0, &OB1};
#pragma unroll
    for (int r = 0; r < 4; ++r)
#pragma unroll
      for (int i = 0; i < 4; ++i) {
        f32x4 v = *(const f32x4*)(sb + (((r * 4 + i) * 16) ^ sx));
#pragma unroll
        for (int c = 0; c < 4; ++c) (*Os[r])[i * 4 + c] += v[c];
      }
  };

  if (tq >= 2) slotW(qg * 2 + (tq - 2));
  __syncthreads();
  if (tq < 2) slotR(qg * 2 + tq);
  __syncthreads();
  if (tq == 1) slotW(qg);
  __syncthreads();
  if (tq == 0) {
    slotR(qg);
    float sA = 0.f, sB = 0.f;
#pragma unroll
    for (int t = 0; t < 4; ++t) {
      sA += Lp[((qg * 4 + t) * 64 + l) * 2];
      sB += Lp[((qg * 4 + t) * 64 + l) * 2 + 1];
    }
    float invA = 1.0f / sA, invB = 1.0f / sB;
    float* orA = out + ((size_t)b * S_ + q0w + lq) * 1024 + hh * 64;
    float* orB = out + ((size_t)b * S_ + q0w + 32 + lq) * 1024 + hh * 64;
#pragma unroll
    for (int r2 = 0; r2 < 4; ++r2) {
      f32x4 a0, a1, b0, b1;
#pragma unroll
      for (int c = 0; c < 4; ++c) {
        a0[c] = OA0[4 * r2 + c] * invA;
        a1[c] = OA1[4 * r2 + c] * invA;
        b0[c] = OB0[4 * r2 + c] * invB;
        b1[c] = OB1[4 * r2 + c] * invB;
      }
      *(f32x4*)&orA[r2 * 8 + h * 4] = a0;
      *(f32x4*)&orA[32 + r2 * 8 + h * 4] = a1;
      *(f32x4*)&orB[r2 * 8 + h * 4] = b0;
      *(f32x4*)&orB[32 + r2 * 8 + h * 4] = b1;
    }
  }
}

// ---------------------------------------------------------------------------
extern "C" void kernel_launch(void* const* d_in, const int* in_sizes, int n_in,
                              void* d_out, int out_size, void* d_ws, size_t ws_size,
                              hipStream_t stream) {
  const float* X = (const float*)d_in[0];
  const float* mask = (const float*)d_in[1];
  const float* Wq = (const float*)d_in[2];
  const float* bq = (const float*)d_in[3];
  const float* Wk = (const float*)d_in[4];
  const float* bk = (const float*)d_in[5];
  const float* Wv = (const float*)d_in[6];
  const float* bv = (const float*)d_in[7];
  float* out = (float*)d_out;

  char* ws = (char*)d_ws;
  unsigned short* Xbf = (unsigned short*)ws;                        // 8 MB
  unsigned short* Wt  = (unsigned short*)(ws + (size_t)(8 << 20));  // 6 MB
  unsigned short* Qw  = (unsigned short*)(ws + (size_t)(14 << 20)); // 8 MB
  unsigned short* Kw  = (unsigned short*)(ws + (size_t)(22 << 20)); // 8 MB
  unsigned short* Vt  = (unsigned short*)(ws + (size_t)(30 << 20)); // 8 MB

  prep<<<dim3(3072 + 2048), dim3(256), 0, stream>>>(X, Wq, Wk, Wv, Xbf, Wt);
  qkv_gemm<<<dim3(N3_ / 128, M_ / 128), dim3(256), 0, stream>>>(
      Xbf, Wt, bq, bk, bv, Qw, Kw, Vt);
  attn_fwd<<<dim3(512), dim3(512), 0, stream>>>(Qw, Kw, Vt, mask, out);
}

// Round 13
// 92.439 us; speedup vs baseline: 2.9383x; 2.9383x over previous
//
#include <hip/hip_runtime.h>

// ---------------------------------------------------------------------------
// MySelfAttention: out = softmax((X Wq)(X Wk)^T / sqrt(dh) + mask) (X Wv)
// B=2, S=2048, H=16, dh=64, DIM=1024. fp32 in/out, bf16 MFMA internally.
// R13: conservative re-bank. attn = R9 verbatim (last fully-green structure:
//      split-T 8 waves, dbuf LDS, base+immediate addressing, 1 barrier/pair);
//      gemm = R7/R9 (green 4 rounds); prep fusion from R11 (green twice).
//      R10/R11/R12 ledger: 2:1-AI (R10) ~wash; 64q/wave spills under 128-VGPR
//      cap (R11); barrier-free global-K/V (R12) fails post-timing validation
//      (out ~ poison after graph replays, mechanism unresolved) -> reverted.
// ---------------------------------------------------------------------------

typedef __attribute__((ext_vector_type(4))) float f32x4;
typedef __attribute__((ext_vector_type(16))) float f32x16;
typedef __attribute__((ext_vector_type(8))) __bf16 bf16x8;

#define DEV static __device__ __forceinline__

constexpr int S_ = 2048;
constexpr int H_ = 16;
constexpr int DH_ = 64;
constexpr int M_ = 2 * S_;       // 4096 rows (b,s)
constexpr int N3_ = 3 * 1024;    // 3072 cols (q|k|v)
constexpr int K_ = 1024;
constexpr float LOG2E = 1.44269504088896340736f;

DEV unsigned short f2bf(float f) {
  unsigned u = __builtin_bit_cast(unsigned, f);
  u += 0x7fffu + ((u >> 16) & 1u);   // round-nearest-even
  return (unsigned short)(u >> 16);
}

DEV unsigned cvt_pk(float lo, float hi) {
  unsigned d;
  asm("v_cvt_pk_bf16_f32 %0, %1, %2" : "=v"(d) : "v"(lo), "v"(hi));
  return d;
}

DEV void gload_lds16(const void* g, void* l) {
  __builtin_amdgcn_global_load_lds(
      (const __attribute__((address_space(1))) unsigned int*)g,
      (__attribute__((address_space(3))) unsigned int*)l, 16, 0, 0);
}

// XOR swizzle: row-major tile with 128B rows, byte ^= (row&7)<<4
DEV int kswz(int row, int colb) { return row * 128 + (colb ^ ((row & 7) << 4)); }

// ---------------------------------------------------------------------------
// Kernel 1: merged prep. id<3072: transpose+convert W; else convert X chunk.
// ---------------------------------------------------------------------------
__global__ __launch_bounds__(256) void prep(
    const float* __restrict__ X, const float* __restrict__ Wq,
    const float* __restrict__ Wk, const float* __restrict__ Wv,
    unsigned short* __restrict__ Xbf, unsigned short* __restrict__ Wt) {
  __shared__ float tile[32][33];
  const int id = blockIdx.x;
  const int tid = threadIdx.x;
  if (id < 3072) {
    int z = id >> 10, rem = id & 1023;
    const float* W = (z == 0) ? Wq : (z == 1) ? Wk : Wv;
    int n0 = (rem & 31) * 32, k0 = (rem >> 5) * 32;
    int tx = tid & 31, ty = tid >> 5;   // 32 x 8
    for (int i = 0; i < 4; ++i)
      tile[ty + i * 8][tx] = W[(size_t)(k0 + ty + i * 8) * 1024 + n0 + tx];
    __syncthreads();
    for (int i = 0; i < 4; ++i)
      Wt[(size_t)(z * 1024 + n0 + ty + i * 8) * 1024 + k0 + tx] =
          f2bf(tile[tx][ty + i * 8]);
  } else {
    int idx = ((id - 3072) * 256 + tid) * 8;
    float4 a = *(const float4*)(X + idx);
    float4 b = *(const float4*)(X + idx + 4);
    unsigned short r[8];
    r[0] = f2bf(a.x); r[1] = f2bf(a.y); r[2] = f2bf(a.z); r[3] = f2bf(a.w);
    r[4] = f2bf(b.x); r[5] = f2bf(b.y); r[6] = f2bf(b.z); r[7] = f2bf(b.w);
    *(uint4*)(Xbf + idx) = *(uint4*)r;
  }
}

// ---------------------------------------------------------------------------
// Kernel 2: QKV GEMM, 128x128 tile, BK=64, LDS XOR-swizzled (R7, green x4).
// Epilogue: bias, Q *= 0.125*log2e, K->[B,H,S,dh], V transposed -> [B,H,dh,S].
// ---------------------------------------------------------------------------
__global__ __launch_bounds__(256, 2) void qkv_gemm(
    const unsigned short* __restrict__ Xbf, const unsigned short* __restrict__ Wt,
    const float* __restrict__ bq, const float* __restrict__ bk,
    const float* __restrict__ bv, unsigned short* __restrict__ Qw,
    unsigned short* __restrict__ Kw, unsigned short* __restrict__ Vt) {
  __shared__ unsigned short Abuf[128 * 64];
  __shared__ unsigned short Bbuf[128 * 64];
  int tid = threadIdx.x;
  int w = tid >> 6, l = tid & 63;
  int row16 = l & 15, kg = l >> 4;
  int mBase = blockIdx.y * 128, nBase = blockIdx.x * 128;
  int wm = w >> 1, wn = w & 1;

  f32x4 acc[4][4] = {};

  const int grow = l >> 3;
  const int gcol = ((l & 7) ^ grow) * 8;

  for (int kt = 0; kt < K_ / 64; ++kt) {
    int k0 = kt * 64;
    __syncthreads();
#pragma unroll
    for (int j = 0; j < 4; ++j) {
      int c1k = w * 4 + j;
      int r = c1k * 8 + grow;
      gload_lds16(Xbf + (size_t)(mBase + r) * K_ + k0 + gcol,
                  (char*)Abuf + c1k * 1024);
      gload_lds16(Wt + (size_t)(nBase + r) * K_ + k0 + gcol,
                  (char*)Bbuf + c1k * 1024);
    }
    __syncthreads();
#pragma unroll
    for (int kk = 0; kk < 2; ++kk) {
      bf16x8 af[4], bfr[4];
#pragma unroll
      for (int m = 0; m < 4; ++m)
        af[m] = *(const bf16x8*)((const char*)Abuf +
                 kswz(wm * 64 + m * 16 + row16, kk * 64 + kg * 16));
#pragma unroll
      for (int n = 0; n < 4; ++n)
        bfr[n] = *(const bf16x8*)((const char*)Bbuf +
                  kswz(wn * 64 + n * 16 + row16, kk * 64 + kg * 16));
#pragma unroll
      for (int m = 0; m < 4; ++m)
#pragma unroll
        for (int n = 0; n < 4; ++n)
          acc[m][n] = __builtin_amdgcn_mfma_f32_16x16x32_bf16(af[m], bfr[n],
                                                              acc[m][n], 0, 0, 0);
    }
  }

#pragma unroll
  for (int n = 0; n < 4; ++n) {
    int gn = nBase + wn * 64 + n * 16 + row16;
    int which = gn >> 10;
    int nn = gn & 1023;
    float bias = (which == 0 ? bq : which == 1 ? bk : bv)[nn];
    unsigned short* dst = (which == 0) ? Qw : (which == 1) ? Kw : Vt;
    float scl = (which == 0) ? 0.125f * LOG2E : 1.0f;
    int hh = nn >> 6, dd = nn & 63;
#pragma unroll
    for (int m = 0; m < 4; ++m) {
      int gm0 = mBase + wm * 64 + m * 16 + kg * 4;
#pragma unroll
      for (int j = 0; j < 4; ++j) {
        int gm = gm0 + j;
        int bb = gm >> 11, ss = gm & 2047;
        float v = (acc[m][n][j] + bias) * scl;
        size_t idx;
        if (which == 2)
          idx = ((size_t)(bb * H_ + hh) * DH_ + dd) * S_ + ss;   // V^T
        else
          idx = ((size_t)(bb * H_ + hh) * S_ + ss) * DH_ + dd;   // Q,K
        dst[idx] = f2bf(v);
      }
    }
  }
}

// ---------------------------------------------------------------------------
// Kernel 3: flash attention (R9 verbatim). 512 blocks (XCD affinity) x 512
// thr (8 waves = 4 qg x 2 thalf). Flat LDS: Ms[0,8K) | Ks[8K,41K) |
// Vs[41K,74K). Base-VGPR + immediate-offset addressing, dbuf via x2 unroll,
// one __syncthreads per pair, additive split-T combine at the end.
// ---------------------------------------------------------------------------
__global__ __launch_bounds__(512, 4) void attn_fwd(
    const unsigned short* __restrict__ Qw, const unsigned short* __restrict__ Kw,
    const unsigned short* __restrict__ Vt, const float* __restrict__ mask,
    float* __restrict__ out) {
  __shared__ __align__(16) char LDS[73728];

  const int tid = threadIdx.x;
  const int w = tid >> 6, l = tid & 63;
  const int qg = w >> 1, thalf = w & 1;
  const int lq = l & 31;
  const int h = l >> 5;
  const int wgid = blockIdx.x;              // 0..511
  const int xcd = wgid & 7, ixd = wgid >> 3;
  const int bh = xcd + 8 * (ixd >> 4);      // 0..31
  const int qt = ixd & 15;                  // 0..15
  const int b = bh >> 4, hh = bh & 15;
  const int q0 = qt * 128 + qg * 32;

  const unsigned short* Kb = Kw + (size_t)bh * S_ * DH_;
  const unsigned short* Vb = Vt + (size_t)bh * DH_ * S_;

  // mask * log2e -> Ms (512 threads, one float4 each)
  {
    float4 mv = *(const float4*)(mask + (size_t)b * S_ + tid * 4);
    mv.x *= LOG2E; mv.y *= LOG2E; mv.z *= LOG2E; mv.w *= LOG2E;
    *(float4*)(LDS + tid * 16) = mv;
  }

  // Q B-fragments (prescaled by 0.125*log2e in GEMM): k = kk*16 + h*8 + j
  bf16x8 qf[4];
  {
    const unsigned short* qrow = Qw + ((size_t)bh * S_ + q0 + lq) * DH_;
#pragma unroll
    for (int kk = 0; kk < 4; ++kk)
      qf[kk] = *(const bf16x8*)(qrow + kk * 16 + h * 8);
  }

  int rb[4];
#pragma unroll
  for (int kk = 0; kk < 4; ++kk)
    rb[kk] = 8192 + thalf * 8192 + lq * 128 + ((kk * 32 + h * 16) ^ ((lq & 7) << 4));
  const int srow = tid >> 3;
  const int tc8 = (tid & 7) * 8;
  const int wb = 8192 + srow * 128 + (((tid & 7) * 16) ^ ((srow & 7) << 4));
  const int mb = thalf * 256 + h * 16;

  // prologue: pair 0 -> regs -> LDS buf0; pair 1 -> regs
  bf16x8 kr[2], vr[2];
#pragma unroll
  for (int j = 0; j < 2; ++j) {
    kr[j] = *(const bf16x8*)(Kb + (size_t)(j * 64 + srow) * DH_ + tc8);
    vr[j] = *(const bf16x8*)(Vb + (size_t)srow * S_ + j * 64 + tc8);
  }
#pragma unroll
  for (int j = 0; j < 2; ++j) {
    *(bf16x8*)(LDS + wb + j * 8192) = kr[j];
    *(bf16x8*)(LDS + wb + 32768 + j * 8192) = vr[j];
  }
#pragma unroll
  for (int j = 0; j < 2; ++j) {
    kr[j] = *(const bf16x8*)(Kb + (size_t)(128 + j * 64 + srow) * DH_ + tc8);
    vr[j] = *(const bf16x8*)(Vb + (size_t)srow * S_ + 128 + j * 64 + tc8);
  }
  __syncthreads();

  float l_run = 0.f;
  f32x16 O0 = {}, O1 = {};

  auto body = [&](int p, int cur) __attribute__((always_inline)) {
    if (p < 15) {
#pragma unroll
      for (int j = 0; j < 2; ++j) {
        *(bf16x8*)(LDS + wb + j * 8192 + (cur ^ 1) * 16384) = kr[j];
        *(bf16x8*)(LDS + wb + 32768 + j * 8192 + (cur ^ 1) * 16384) = vr[j];
      }
      if (p < 14) {
        const int tn = (p + 2) * 128;
#pragma unroll
        for (int j = 0; j < 2; ++j) {
          kr[j] = *(const bf16x8*)(Kb + (size_t)(tn + j * 64 + srow) * DH_ + tc8);
          vr[j] = *(const bf16x8*)(Vb + (size_t)srow * S_ + tn + j * 64 + tc8);
        }
      }
    }

    const int mo = mb + p * 512;
    f32x16 p0, p1;
#pragma unroll
    for (int r2 = 0; r2 < 4; ++r2) {
      f32x4 a = *(const f32x4*)(LDS + mo + r2 * 32);
      f32x4 bq4 = *(const f32x4*)(LDS + mo + 128 + r2 * 32);
#pragma unroll
      for (int c = 0; c < 4; ++c) { p0[4 * r2 + c] = a[c]; p1[4 * r2 + c] = bq4[c]; }
    }

    __builtin_amdgcn_s_setprio(1);
#pragma unroll
    for (int kk = 0; kk < 4; ++kk) {
      bf16x8 kf0 = *(const bf16x8*)(LDS + rb[kk] + cur * 16384);
      bf16x8 kf1 = *(const bf16x8*)(LDS + rb[kk] + 4096 + cur * 16384);
      p0 = __builtin_amdgcn_mfma_f32_32x32x16_bf16(kf0, qf[kk], p0, 0, 0, 0);
      p1 = __builtin_amdgcn_mfma_f32_32x32x16_bf16(kf1, qf[kk], p1, 0, 0, 0);
    }
    __builtin_amdgcn_s_setprio(0);

#pragma unroll
    for (int i = 0; i < 16; ++i) {
      p0[i] = __builtin_amdgcn_exp2f(p0[i]);
      p1[i] = __builtin_amdgcn_exp2f(p1[i]);
    }

    float s8[8];
#pragma unroll
    for (int i = 0; i < 8; ++i)
      s8[i] = (p0[i] + p0[i + 8]) + (p1[i] + p1[i + 8]);
    float rs = ((s8[0] + s8[1]) + (s8[2] + s8[3])) +
               ((s8[4] + s8[5]) + (s8[6] + s8[7]));
    rs += __shfl_xor(rs, 32, 64);
    l_run += rs;

    unsigned w0[8], w1[8];
#pragma unroll
    for (int r2 = 0; r2 < 4; ++r2) {
      w0[2 * r2]     = cvt_pk(p0[4 * r2 + 0], p0[4 * r2 + 1]);
      w0[2 * r2 + 1] = cvt_pk(p0[4 * r2 + 2], p0[4 * r2 + 3]);
      w1[2 * r2]     = cvt_pk(p1[4 * r2 + 0], p1[4 * r2 + 1]);
      w1[2 * r2 + 1] = cvt_pk(p1[4 * r2 + 2], p1[4 * r2 + 3]);
    }

    __builtin_amdgcn_s_setprio(1);
#pragma unroll
    for (int s = 0; s < 4; ++s) {
      const unsigned* W = (s < 2) ? w0 : w1;
      const int base = (s & 1) * 4;
      unsigned send0 = h ? W[base + 0] : W[base + 2];
      unsigned send1 = h ? W[base + 1] : W[base + 3];
      unsigned c0 = (unsigned)__shfl_xor((int)send0, 32, 64);
      unsigned c1 = (unsigned)__shfl_xor((int)send1, 32, 64);
      uint4 fw;
      fw.x = h ? c0 : W[base + 0];
      fw.y = h ? c1 : W[base + 1];
      fw.z = h ? W[base + 2] : c0;
      fw.w = h ? W[base + 3] : c1;
      bf16x8 pf = __builtin_bit_cast(bf16x8, fw);
      bf16x8 vf0 = *(const bf16x8*)(LDS + rb[s] + 32768 + cur * 16384);
      O0 = __builtin_amdgcn_mfma_f32_32x32x16_bf16(vf0, pf, O0, 0, 0, 0);
      bf16x8 vf1 = *(const bf16x8*)(LDS + rb[s] + 36864 + cur * 16384);
      O1 = __builtin_amdgcn_mfma_f32_32x32x16_bf16(vf1, pf, O1, 0, 0, 0);
    }
    __builtin_amdgcn_s_setprio(0);

    __syncthreads();
  };

#pragma unroll 1
  for (int pp = 0; pp < 8; ++pp) {
    body(2 * pp, 0);
    body(2 * pp + 1, 1);
  }

  // ---- combine thalf halves additively (no-max softmax partials add)
  char* Osc = LDS + 8192;
  float* Mp = (float*)LDS;
  const int sbase = qg * 8192 + l * 128;
  const int sx = (l & 7) << 4;
  if (thalf == 1) {
#pragma unroll
    for (int i = 0; i < 4; ++i) {
      f32x4 v;
#pragma unroll
      for (int c = 0; c < 4; ++c) v[c] = O0[i * 4 + c];
      *(f32x4*)(Osc + sbase + ((i * 16) ^ sx)) = v;
    }
#pragma unroll
    for (int i = 0; i < 4; ++i) {
      f32x4 v;
#pragma unroll
      for (int c = 0; c < 4; ++c) v[c] = O1[i * 4 + c];
      *(f32x4*)(Osc + sbase + (((i + 4) * 16) ^ sx)) = v;
    }
    Mp[qg * 64 + l] = l_run;
  }
  __syncthreads();
  if (thalf == 0) {
#pragma unroll
    for (int i = 0; i < 4; ++i) {
      f32x4 v = *(const f32x4*)(Osc + sbase + ((i * 16) ^ sx));
#pragma unroll
      for (int c = 0; c < 4; ++c) O0[i * 4 + c] += v[c];
    }
#pragma unroll
    for (int i = 0; i < 4; ++i) {
      f32x4 v = *(const f32x4*)(Osc + sbase + (((i + 4) * 16) ^ sx));
#pragma unroll
      for (int c = 0; c < 4; ++c) O1[i * 4 + c] += v[c];
    }
    l_run += Mp[qg * 64 + l];

    float inv = 1.0f / l_run;
    float* orow = out + ((size_t)b * S_ + q0 + lq) * 1024 + hh * 64;
#pragma unroll
    for (int r2 = 0; r2 < 4; ++r2) {
      f32x4 v0, v1;
#pragma unroll
      for (int c = 0; c < 4; ++c) {
        v0[c] = O0[4 * r2 + c] * inv;
        v1[c] = O1[4 * r2 + c] * inv;
      }
      *(f32x4*)&orow[r2 * 8 + h * 4] = v0;
      *(f32x4*)&orow[32 + r2 * 8 + h * 4] = v1;
    }
  }
}

// ---------------------------------------------------------------------------
extern "C" void kernel_launch(void* const* d_in, const int* in_sizes, int n_in,
                              void* d_out, int out_size, void* d_ws, size_t ws_size,
                              hipStream_t stream) {
  const float* X = (const float*)d_in[0];
  const float* mask = (const float*)d_in[1];
  const float* Wq = (const float*)d_in[2];
  const float* bq = (const float*)d_in[3];
  const float* Wk = (const float*)d_in[4];
  const float* bk = (const float*)d_in[5];
  const float* Wv = (const float*)d_in[6];
  const float* bv = (const float*)d_in[7];
  float* out = (float*)d_out;

  char* ws = (char*)d_ws;
  unsigned short* Xbf = (unsigned short*)ws;                        // 8 MB
  unsigned short* Wt  = (unsigned short*)(ws + (size_t)(8 << 20));  // 6 MB
  unsigned short* Qw  = (unsigned short*)(ws + (size_t)(14 << 20)); // 8 MB
  unsigned short* Kw  = (unsigned short*)(ws + (size_t)(22 << 20)); // 8 MB
  unsigned short* Vt  = (unsigned short*)(ws + (size_t)(30 << 20)); // 8 MB

  prep<<<dim3(3072 + 2048), dim3(256), 0, stream>>>(X, Wq, Wk, Wv, Xbf, Wt);
  qkv_gemm<<<dim3(N3_ / 128, M_ / 128), dim3(256), 0, stream>>>(
      Xbf, Wt, bq, bk, bv, Qw, Kw, Vt);
  attn_fwd<<<dim3(512), dim3(512), 0, stream>>>(Qw, Kw, Vt, mask, out);
}